// Round 1
// baseline (388.871 us; speedup 1.0000x reference)
//
#include <hip/hip_runtime.h>
#include <hip/hip_bf16.h>
#include <stdint.h>

// Problem constants
#define B_   4
#define T_   2048
#define D_   1024
#define H_   16
#define DH_  64
#define MTOT (B_ * T_)          // 8192 rows
#define NQKV 3072               // fused QKV output cols

typedef __attribute__((ext_vector_type(8))) __bf16 bf16x8;
typedef __attribute__((ext_vector_type(4))) float f32x4;
typedef __attribute__((ext_vector_type(4))) float f4v;
typedef __attribute__((ext_vector_type(4))) unsigned short us4;
typedef __attribute__((ext_vector_type(8))) unsigned short us8;

static __device__ __forceinline__ unsigned short f2bf(float f) {
  __hip_bfloat16 h = __float2bfloat16(f);
  return __builtin_bit_cast(unsigned short, h);
}

static __device__ __forceinline__ void async16(const void* g, void* l) {
  __builtin_amdgcn_global_load_lds(
      (const __attribute__((address_space(1))) void*)g,
      (__attribute__((address_space(3))) void*)l, 16, 0, 0);
}

// ---------------- fp32 -> bf16 convert (x4 vectorized) ----------------
__global__ void cvt_kernel(const float* __restrict__ src,
                           unsigned short* __restrict__ dst, int n4) {
  int i = blockIdx.x * blockDim.x + threadIdx.x;
  if (i >= n4) return;
  f4v v = reinterpret_cast<const f4v*>(src)[i];
  us4 o;
  o.x = f2bf(v.x); o.y = f2bf(v.y); o.z = f2bf(v.z); o.w = f2bf(v.w);
  reinterpret_cast<us4*>(dst)[i] = o;
}

// ---------------- bf16 GEMM, C = A * B^T (both stored K-major) ----------------
// m97 structure: 128x128 tile, BK=32, 4 waves each computing 64x64,
// global_load_lds width-16 staging, mfma_f32_16x16x32_bf16.
template <int F32OUT>
__global__ __launch_bounds__(256) void gemm_bt(
    const unsigned short* __restrict__ A,   // [M][K] bf16 bits
    const unsigned short* __restrict__ Bw,  // [N][K] bf16 bits
    unsigned short* __restrict__ Cb,        // bf16 out (if !F32OUT)
    float* __restrict__ Cf,                 // f32 out (if F32OUT)
    const float* __restrict__ bias,         // nullable
    int K, int N) {
  __shared__ __align__(16) unsigned short As[128 * 32];
  __shared__ __align__(16) unsigned short Bs[128 * 32];

  const int t = threadIdx.x;
  const int lane = t & 63;
  const int w = t >> 6;
  const int lr = lane & 15;
  const int lg = lane >> 4;
  const int wm = w >> 1;
  const int wn = w & 1;
  const int m0 = blockIdx.y * 128;
  const int n0 = blockIdx.x * 128;

  f32x4 acc[4][4];
#pragma unroll
  for (int i = 0; i < 4; ++i)
#pragma unroll
    for (int j = 0; j < 4; ++j) acc[i][j] = (f32x4){0.f, 0.f, 0.f, 0.f};

  const int srow = t >> 2;          // 0..63
  const int scol = (t & 3) * 8;     // 0,8,16,24 elems
  const unsigned short* ga = A + (size_t)(m0 + srow) * K + scol;
  const unsigned short* gb = Bw + (size_t)(n0 + srow) * K + scol;

  for (int k0 = 0; k0 < K; k0 += 32) {
    async16(ga + k0,                 &As[t * 8]);
    async16(ga + k0 + (size_t)64 * K, &As[2048 + t * 8]);
    async16(gb + k0,                 &Bs[t * 8]);
    async16(gb + k0 + (size_t)64 * K, &Bs[2048 + t * 8]);
    __syncthreads();

    bf16x8 af[4], bfr[4];
#pragma unroll
    for (int mi = 0; mi < 4; ++mi)
      af[mi] = *(const bf16x8*)&As[(wm * 64 + mi * 16 + lr) * 32 + lg * 8];
#pragma unroll
    for (int ni = 0; ni < 4; ++ni)
      bfr[ni] = *(const bf16x8*)&Bs[(wn * 64 + ni * 16 + lr) * 32 + lg * 8];
#pragma unroll
    for (int mi = 0; mi < 4; ++mi)
#pragma unroll
      for (int ni = 0; ni < 4; ++ni)
        acc[mi][ni] = __builtin_amdgcn_mfma_f32_16x16x32_bf16(
            af[mi], bfr[ni], acc[mi][ni], 0, 0, 0);
    __syncthreads();
  }

  // epilogue: D layout col=lane&15, row=(lane>>4)*4+r
#pragma unroll
  for (int mi = 0; mi < 4; ++mi) {
    const int row = m0 + wm * 64 + mi * 16 + lg * 4;
#pragma unroll
    for (int ni = 0; ni < 4; ++ni) {
      const int col = n0 + wn * 64 + ni * 16 + lr;
#pragma unroll
      for (int r = 0; r < 4; ++r) {
        if (F32OUT)
          Cf[(size_t)(row + r) * N + col] = acc[mi][ni][r] + bias[col];
        else
          Cb[(size_t)(row + r) * N + col] = f2bf(acc[mi][ni][r]);
      }
    }
  }
}

// ---------------- causal flash attention ----------------
// qkv: [8192][3072] bf16 (cols: 0..1023 Q, 1024..2047 K, 2048..3071 V; col=h*64+d)
// ob : [8192][1024] bf16 attention output (col = h*64+d)
__global__ __launch_bounds__(256) void attn_kernel(
    const unsigned short* __restrict__ qkv, unsigned short* __restrict__ ob) {
  const int pair = blockIdx.y;  // b*H + h
  const int b = pair >> 4;
  const int h = pair & 15;
  const int qb = blockIdx.x;
  const int q0 = qb * 64;
  const int t = threadIdx.x;
  const int lane = t & 63;
  const int w = t >> 6;
  const int lr = lane & 15;
  const int lg = lane >> 4;

  __shared__ __align__(16) unsigned short Klds[64][72];
  __shared__ __align__(16) unsigned short Vt[64][72];     // V transposed [d][kv]
  __shared__ __align__(16) unsigned short Plds[4][16][72];

  // Q fragments, A-layout: row = lane&15, k = (lane>>4)*8 (+32 for second frag)
  const size_t qrow = (size_t)(b * T_ + q0 + w * 16 + lr) * NQKV + h * 64;
  const bf16x8 qf0 = *(const bf16x8*)&qkv[qrow + lg * 8];
  const bf16x8 qf1 = *(const bf16x8*)&qkv[qrow + 32 + lg * 8];

  float m_i[4], l_i[4];
  f32x4 o[4];
#pragma unroll
  for (int r = 0; r < 4; ++r) { m_i[r] = -INFINITY; l_i[r] = 0.f; }
#pragma unroll
  for (int dj = 0; dj < 4; ++dj) o[dj] = (f32x4){0.f, 0.f, 0.f, 0.f};

  const int srow = t >> 2;        // 0..63 kv row
  const int scol = (t & 3) * 16;  // 0,16,32,48 d base
  const int nkv = qb + 1;

  for (int kt = 0; kt < nkv; ++kt) {
    const int kv0 = kt * 64;
    // ---- stage K (row-major) and V (transposed) ----
    const unsigned short* kr =
        qkv + (size_t)(b * T_ + kv0 + srow) * NQKV + 1024 + h * 64 + scol;
    us8 ka = *(const us8*)kr;
    us8 kb = *(const us8*)(kr + 8);
    *(us8*)&Klds[srow][scol] = ka;
    *(us8*)&Klds[srow][scol + 8] = kb;
    const unsigned short* vr = kr + 1024;
    us8 va = *(const us8*)vr;
    us8 vb = *(const us8*)(vr + 8);
#pragma unroll
    for (int i = 0; i < 8; ++i) {
      Vt[scol + i][srow] = va[i];
      Vt[scol + 8 + i][srow] = vb[i];
    }
    __syncthreads();

    // ---- S = Q K^T  (16q x 64kv per wave) ----
    f32x4 s[4];
#pragma unroll
    for (int j = 0; j < 4; ++j) {
      s[j] = (f32x4){0.f, 0.f, 0.f, 0.f};
      bf16x8 kf0 = *(const bf16x8*)&Klds[j * 16 + lr][lg * 8];
      bf16x8 kf1 = *(const bf16x8*)&Klds[j * 16 + lr][32 + lg * 8];
      s[j] = __builtin_amdgcn_mfma_f32_16x16x32_bf16(qf0, kf0, s[j], 0, 0, 0);
      s[j] = __builtin_amdgcn_mfma_f32_16x16x32_bf16(qf1, kf1, s[j], 0, 0, 0);
    }

    // ---- scale + causal mask (only diagonal tile needs masking) ----
    const bool diag = (kv0 == q0);
#pragma unroll
    for (int j = 0; j < 4; ++j) {
#pragma unroll
      for (int r = 0; r < 4; ++r) {
        float x = s[j][r] * 0.125f;  // Dh^-0.5
        if (diag) {
          int kvg = kv0 + j * 16 + lr;
          int qg = q0 + w * 16 + lg * 4 + r;
          if (kvg > qg) x = -INFINITY;
        }
        s[j][r] = x;
      }
    }

    // ---- online softmax (rows live in 16-lane groups) ----
    float rm[4], alpha[4], rs[4];
#pragma unroll
    for (int r = 0; r < 4; ++r) {
      rm[r] = fmaxf(fmaxf(s[0][r], s[1][r]), fmaxf(s[2][r], s[3][r]));
      rm[r] = fmaxf(rm[r], __shfl_xor(rm[r], 1));
      rm[r] = fmaxf(rm[r], __shfl_xor(rm[r], 2));
      rm[r] = fmaxf(rm[r], __shfl_xor(rm[r], 4));
      rm[r] = fmaxf(rm[r], __shfl_xor(rm[r], 8));
      float mn = fmaxf(m_i[r], rm[r]);
      alpha[r] = __expf(m_i[r] - mn);
      m_i[r] = mn;
      rs[r] = 0.f;
    }
#pragma unroll
    for (int j = 0; j < 4; ++j) {
#pragma unroll
      for (int r = 0; r < 4; ++r) {
        float p = __expf(s[j][r] - m_i[r]);
        rs[r] += p;
        Plds[w][lg * 4 + r][j * 16 + lr] = f2bf(p);
      }
    }
#pragma unroll
    for (int r = 0; r < 4; ++r) {
      rs[r] += __shfl_xor(rs[r], 1);
      rs[r] += __shfl_xor(rs[r], 2);
      rs[r] += __shfl_xor(rs[r], 4);
      rs[r] += __shfl_xor(rs[r], 8);
      l_i[r] = l_i[r] * alpha[r] + rs[r];
    }
    const f32x4 av = {alpha[0], alpha[1], alpha[2], alpha[3]};
#pragma unroll
    for (int dj = 0; dj < 4; ++dj) o[dj] *= av;

    // ---- O += P V ----
    bf16x8 pa0 = *(const bf16x8*)&Plds[w][lr][lg * 8];
    bf16x8 pa1 = *(const bf16x8*)&Plds[w][lr][32 + lg * 8];
#pragma unroll
    for (int dj = 0; dj < 4; ++dj) {
      bf16x8 vf0 = *(const bf16x8*)&Vt[dj * 16 + lr][lg * 8];
      bf16x8 vf1 = *(const bf16x8*)&Vt[dj * 16 + lr][32 + lg * 8];
      o[dj] = __builtin_amdgcn_mfma_f32_16x16x32_bf16(pa0, vf0, o[dj], 0, 0, 0);
      o[dj] = __builtin_amdgcn_mfma_f32_16x16x32_bf16(pa1, vf1, o[dj], 0, 0, 0);
    }
    __syncthreads();  // protect K/V tiles before next staging
  }

  // ---- epilogue: normalize and store ----
#pragma unroll
  for (int dj = 0; dj < 4; ++dj) {
#pragma unroll
    for (int r = 0; r < 4; ++r) {
      float val = o[dj][r] / l_i[r];
      int qg = q0 + w * 16 + lg * 4 + r;
      ob[(size_t)(b * T_ + qg) * 1024 + h * 64 + dj * 16 + lr] = f2bf(val);
    }
  }
}

// ---------------- host launch ----------------
extern "C" void kernel_launch(void* const* d_in, const int* in_sizes, int n_in,
                              void* d_out, int out_size, void* d_ws,
                              size_t ws_size, hipStream_t stream) {
  const float* x = (const float*)d_in[0];
  const float* Wq = (const float*)d_in[1];
  const float* Wk = (const float*)d_in[2];
  const float* Wv = (const float*)d_in[3];
  const float* Wo = (const float*)d_in[4];
  const float* bo = (const float*)d_in[5];
  float* out = (float*)d_out;

  // workspace layout (bytes)
  char* ws = (char*)d_ws;
  unsigned short* xb   = (unsigned short*)(ws + 0);          // 16 MB
  unsigned short* wqkv = (unsigned short*)(ws + 16777216);   // 6 MB
  unsigned short* wo   = (unsigned short*)(ws + 23068672);   // 2 MB
  unsigned short* qkv  = (unsigned short*)(ws + 25165824);   // 48 MB
  unsigned short* ob   = (unsigned short*)(ws + 75497472);   // 16 MB
  if (ws_size < 92274688u) return;  // insufficient scratch -> visible failure

  // convert inputs to bf16 (and concat Wq/Wk/Wv rows)
  cvt_kernel<<<8192, 256, 0, stream>>>(x, xb, 2097152);
  cvt_kernel<<<1024, 256, 0, stream>>>(Wq, wqkv, 262144);
  cvt_kernel<<<1024, 256, 0, stream>>>(Wk, wqkv + 1048576, 262144);
  cvt_kernel<<<1024, 256, 0, stream>>>(Wv, wqkv + 2097152, 262144);
  cvt_kernel<<<1024, 256, 0, stream>>>(Wo, wo, 262144);

  // fused QKV projection: [8192 x 3072] = xb[8192x1024] * wqkv[3072x1024]^T
  gemm_bt<0><<<dim3(NQKV / 128, MTOT / 128), 256, 0, stream>>>(
      xb, wqkv, qkv, nullptr, nullptr, 1024, NQKV);

  // causal flash attention
  attn_kernel<<<dim3(T_ / 64, B_ * H_), 256, 0, stream>>>(qkv, ob);

  // output projection + bias: [8192 x 1024] f32
  gemm_bt<1><<<dim3(1024 / 128, MTOT / 128), 256, 0, stream>>>(
      ob, wo, nullptr, out, bo, 1024, 1024);
}

// Round 2
// 207.967 us; speedup vs baseline: 1.8699x; 1.8699x over previous
//
#include <hip/hip_runtime.h>
#include <hip/hip_bf16.h>
#include <stdint.h>

// Problem constants
#define B_   4
#define T_   2048
#define H_   16
#define MTOT (B_ * T_)          // 8192 rows
#define NQKV 3072               // fused QKV output cols
#define QSC  0.18033688f        // 0.125 * log2(e): fold softmax scale + exp2 conversion into Q

typedef __attribute__((ext_vector_type(8))) __bf16 bf16x8;
typedef __attribute__((ext_vector_type(4))) float f32x4;
typedef __attribute__((ext_vector_type(16))) float f32x16;
typedef __attribute__((ext_vector_type(4))) float f4v;
typedef __attribute__((ext_vector_type(4))) unsigned short us4;
typedef __attribute__((ext_vector_type(8))) unsigned short us8;
typedef __attribute__((ext_vector_type(4))) unsigned int u32x4;

static __device__ __forceinline__ unsigned short f2bf(float f) {
  __hip_bfloat16 h = __float2bfloat16(f);
  return __builtin_bit_cast(unsigned short, h);
}

static __device__ __forceinline__ void async16(const void* g, void* l) {
  __builtin_amdgcn_global_load_lds(
      (const __attribute__((address_space(1))) void*)g,
      (__attribute__((address_space(3))) void*)l, 16, 0, 0);
}

// ---------------- fp32 -> bf16 convert (x4 vectorized) ----------------
__global__ void cvt_kernel(const float* __restrict__ src,
                           unsigned short* __restrict__ dst, int n4) {
  int i = blockIdx.x * blockDim.x + threadIdx.x;
  if (i >= n4) return;
  f4v v = reinterpret_cast<const f4v*>(src)[i];
  us4 o;
  o.x = f2bf(v.x); o.y = f2bf(v.y); o.z = f2bf(v.z); o.w = f2bf(v.w);
  reinterpret_cast<us4*>(dst)[i] = o;
}

// ---------------- bf16 GEMM, C = A * B^T (both stored K-major) ----------------
// MODE 0: bf16 output, cols < 1024 (Q) scaled by QSC.  MODE 1: f32 output + bias.
template <int MODE>
__global__ __launch_bounds__(256) void gemm_bt(
    const unsigned short* __restrict__ A,   // [M][K] bf16 bits
    const unsigned short* __restrict__ Bw,  // [N][K] bf16 bits
    unsigned short* __restrict__ Cb,        // bf16 out (MODE 0)
    float* __restrict__ Cf,                 // f32 out (MODE 1)
    const float* __restrict__ bias,         // MODE 1
    int K, int N) {
  __shared__ __align__(16) unsigned short As[128 * 32];
  __shared__ __align__(16) unsigned short Bs[128 * 32];

  const int t = threadIdx.x;
  const int lane = t & 63;
  const int w = t >> 6;
  const int lr = lane & 15;
  const int lg = lane >> 4;
  const int wm = w >> 1;
  const int wn = w & 1;
  const int m0 = blockIdx.y * 128;
  const int n0 = blockIdx.x * 128;

  f32x4 acc[4][4];
#pragma unroll
  for (int i = 0; i < 4; ++i)
#pragma unroll
    for (int j = 0; j < 4; ++j) acc[i][j] = (f32x4){0.f, 0.f, 0.f, 0.f};

  const int srow = t >> 2;          // 0..63
  const int scol = (t & 3) * 8;     // 0,8,16,24 elems
  const unsigned short* ga = A + (size_t)(m0 + srow) * K + scol;
  const unsigned short* gb = Bw + (size_t)(n0 + srow) * K + scol;

  for (int k0 = 0; k0 < K; k0 += 32) {
    async16(ga + k0,                  &As[t * 8]);
    async16(ga + k0 + (size_t)64 * K, &As[2048 + t * 8]);
    async16(gb + k0,                  &Bs[t * 8]);
    async16(gb + k0 + (size_t)64 * K, &Bs[2048 + t * 8]);
    __syncthreads();

    bf16x8 af[4], bfr[4];
#pragma unroll
    for (int mi = 0; mi < 4; ++mi)
      af[mi] = *(const bf16x8*)&As[(wm * 64 + mi * 16 + lr) * 32 + lg * 8];
#pragma unroll
    for (int ni = 0; ni < 4; ++ni)
      bfr[ni] = *(const bf16x8*)&Bs[(wn * 64 + ni * 16 + lr) * 32 + lg * 8];
#pragma unroll
    for (int mi = 0; mi < 4; ++mi)
#pragma unroll
      for (int ni = 0; ni < 4; ++ni)
        acc[mi][ni] = __builtin_amdgcn_mfma_f32_16x16x32_bf16(
            af[mi], bfr[ni], acc[mi][ni], 0, 0, 0);
    __syncthreads();
  }

  // epilogue: D layout col=lane&15, row=(lane>>4)*4+r
#pragma unroll
  for (int mi = 0; mi < 4; ++mi) {
    const int row = m0 + wm * 64 + mi * 16 + lg * 4;
#pragma unroll
    for (int ni = 0; ni < 4; ++ni) {
      const int col = n0 + wn * 64 + ni * 16 + lr;
#pragma unroll
      for (int r = 0; r < 4; ++r) {
        if (MODE == 1) {
          Cf[(size_t)(row + r) * N + col] = acc[mi][ni][r] + bias[col];
        } else {
          float v = acc[mi][ni][r];
          if (col < 1024) v *= QSC;   // pre-scale Q for exp2-space softmax
          Cb[(size_t)(row + r) * N + col] = f2bf(v);
        }
      }
    }
  }
}

// ---------------- causal flash attention (8 waves x 32 q-rows, 32x32 MFMA) ----
// qkv: [8192][3072] bf16 (cols: 0..1023 Q (pre-scaled), 1024..2047 K, 2048..3071 V)
// ob : [8192][1024] bf16 attention output (col = h*64+d)
//
// Swapped-operand scheme: S^T = K·Q^T via mfma(A=K, B=Q) -> lane owns q-col
// (lane&31); softmax fully in-register; P redistributed via cvt_pk +
// v_permlane32_swap_b32; O^T = V^T·P^T via mfma(A=V^T from swizzled LDS, B=P^T).
__global__ __launch_bounds__(512, 2) void attn_kernel(
    const unsigned short* __restrict__ qkv, unsigned short* __restrict__ ob) {
  const int bid = blockIdx.x;
  const int qg = 7 - (bid >> 6);      // longest blocks dispatch first
  const int pair = bid & 63;
  const int b = pair >> 4;
  const int h = pair & 15;
  const int t = threadIdx.x;
  const int w = t >> 6;
  const int lane = t & 63;
  const int l31 = lane & 31;
  const int hi = lane >> 5;

  const int q0w = qg * 256 + w * 32;      // wave's q strip
  const int myBound = qg * 4 + (w >> 1);  // last kv-tile this wave computes
  const int NT = qg * 4 + 4;              // kv tiles staged by block

  __shared__ __align__(16) unsigned short Ks[2][64 * 64];
  __shared__ __align__(16) unsigned short Vs[2][64 * 64];

  const size_t rowbase = (size_t)(b * T_) * NQKV;

  // ---- Q B-fragments (held all loop): col=q=l31, k=d = m*16 + hi*8 + i ----
  bf16x8 Qf[4];
  {
    const unsigned short* qp =
        qkv + rowbase + (size_t)(q0w + l31) * NQKV + h * 64 + hi * 8;
#pragma unroll
    for (int m = 0; m < 4; ++m) Qf[m] = *(const bf16x8*)(qp + m * 16);
  }

  // ---- staging geometry ----
  // K via global_load_lds: thread t stages LDS chunk t; chunk (row<<3)|s holds
  // global d-chunk g = s ^ (row&7)  (XOR swizzle -> conflict-free ds_read_b128)
  const int krow = t >> 3;
  const int kg = (t & 7) ^ (krow & 7);
  const unsigned short* kbase =
      qkv + rowbase + 1024 + h * 64 + kg * 8 + (size_t)krow * NQKV;
  // V: thread loads row kvr, d-chunk dc; scatter-transpose into Vs with
  // elem(d,kv) = d*64 + (((kv>>3) ^ (d>>3) ^ d)&7)*8 + (kv&7)
  const int kvr = t >> 3;
  const int dc = t & 7;
  const unsigned short* vbase =
      qkv + rowbase + 2048 + h * 64 + dc * 8 + (size_t)kvr * NQKV;

  float m_i = -INFINITY, l_i = 0.f;
  f32x16 o[2];
#pragma unroll
  for (int r = 0; r < 16; ++r) { o[0][r] = 0.f; o[1][r] = 0.f; }

  // ---- prologue: stage tile 0 into buffer 0 ----
  {
    async16(kbase, &Ks[0][t * 8]);
    us8 v = *(const us8*)vbase;
#pragma unroll
    for (int i = 0; i < 8; ++i) {
      const int drow = dc * 8 + i;
      const int swz = ((kvr >> 3) ^ dc ^ i) & 7;
      Vs[0][drow * 64 + swz * 8 + (kvr & 7)] = v[i];
    }
  }

  int cur = 0;
  for (int kt = 0; kt < NT; ++kt) {
    __syncthreads();  // buf[cur] ready (drains async K + V ds_writes)

    const bool pf = (kt + 1 < NT);
    us8 vreg;
    if (pf) {
      const size_t off = (size_t)(kt + 1) * 64 * NQKV;
      async16(kbase + off, &Ks[cur ^ 1][t * 8]);
      vreg = *(const us8*)(vbase + off);
    }

    if (kt <= myBound) {
      const unsigned short* Kb = Ks[cur];
      const unsigned short* Vb = Vs[cur];

      // ---- S^T[kv][q] : 2 kv-subtiles of 32 ----
      f32x16 a[2];
#pragma unroll
      for (int r = 0; r < 16; ++r) { a[0][r] = 0.f; a[1][r] = 0.f; }
#pragma unroll
      for (int kt2 = 0; kt2 < 2; ++kt2) {
        const int row = kt2 * 32 + l31;
        const int rb = row * 64;
        const int r7 = row & 7;
#pragma unroll
        for (int m = 0; m < 4; ++m) {
          bf16x8 kf = *(const bf16x8*)&Kb[rb + (((m << 1) | hi) ^ r7) * 8];
          a[kt2] = __builtin_amdgcn_mfma_f32_32x32x16_bf16(kf, Qf[m], a[kt2], 0, 0, 0);
        }
      }

      // ---- causal mask: only the diagonal-crossing tile ----
      if (kt == myBound) {
        const int qglob = q0w + l31;
#pragma unroll
        for (int kt2 = 0; kt2 < 2; ++kt2)
#pragma unroll
          for (int r = 0; r < 16; ++r) {
            const int kvg = kt * 64 + kt2 * 32 + (r & 3) + ((r >> 2) << 3) + (hi << 2);
            if (kvg > qglob) a[kt2][r] = -INFINITY;
          }
      }

      // ---- online softmax, lane-local (q-col = l31; partner = lane^32) ----
      float mx = a[0][0];
#pragma unroll
      for (int r = 1; r < 16; ++r) mx = fmaxf(mx, a[0][r]);
#pragma unroll
      for (int r = 0; r < 16; ++r) mx = fmaxf(mx, a[1][r]);
      mx = fmaxf(mx, __shfl_xor(mx, 32));
      const float mnew = fmaxf(m_i, mx);
      const float alpha = exp2f(m_i - mnew);
      m_i = mnew;

      float rs = 0.f;
#pragma unroll
      for (int kt2 = 0; kt2 < 2; ++kt2)
#pragma unroll
        for (int r = 0; r < 16; ++r) {
          const float p = exp2f(a[kt2][r] - mnew);
          a[kt2][r] = p;
          rs += p;
        }
      rs += __shfl_xor(rs, 32);
      l_i = l_i * alpha + rs;

#pragma unroll
      for (int r = 0; r < 16; ++r) { o[0][r] *= alpha; o[1][r] *= alpha; }

      // ---- P^T B-fragments: cvt_pk pairs + permlane32_swap half-exchange ----
      bf16x8 Pf[4];
#pragma unroll
      for (int m = 0; m < 4; ++m) {
        const int rb2 = (m & 1) * 8;
        uint32_t u0, u1, u2, u3;
        const f32x16& s = (m >> 1) ? a[1] : a[0];
        asm("v_cvt_pk_bf16_f32 %0, %1, %2" : "=v"(u0) : "v"(s[rb2 + 0]), "v"(s[rb2 + 1]));
        asm("v_cvt_pk_bf16_f32 %0, %1, %2" : "=v"(u1) : "v"(s[rb2 + 2]), "v"(s[rb2 + 3]));
        asm("v_cvt_pk_bf16_f32 %0, %1, %2" : "=v"(u2) : "v"(s[rb2 + 4]), "v"(s[rb2 + 5]));
        asm("v_cvt_pk_bf16_f32 %0, %1, %2" : "=v"(u3) : "v"(s[rb2 + 6]), "v"(s[rb2 + 7]));
        asm("v_permlane32_swap_b32 %0, %1" : "+v"(u0), "+v"(u2));
        asm("v_permlane32_swap_b32 %0, %1" : "+v"(u1), "+v"(u3));
        u32x4 pw = {u0, u1, u2, u3};
        Pf[m] = __builtin_bit_cast(bf16x8, pw);
      }

      // ---- O^T += V^T P^T ----
#pragma unroll
      for (int dt = 0; dt < 2; ++dt) {
        const int d = dt * 32 + l31;
        const int base = d * 64;
        const int dsw = ((d >> 3) ^ d) & 7;
#pragma unroll
        for (int m = 0; m < 4; ++m) {
          bf16x8 vf = *(const bf16x8*)&Vb[base + ((((m << 1) | hi) ^ dsw) & 7) * 8];
          o[dt] = __builtin_amdgcn_mfma_f32_32x32x16_bf16(vf, Pf[m], o[dt], 0, 0, 0);
        }
      }
    }

    if (pf) {
#pragma unroll
      for (int i = 0; i < 8; ++i) {
        const int drow = dc * 8 + i;
        const int swz = ((kvr >> 3) ^ dc ^ i) & 7;
        Vs[cur ^ 1][drow * 64 + swz * 8 + (kvr & 7)] = vreg[i];
      }
    }
    cur ^= 1;
  }

  // ---- epilogue: normalize, pack to bf16, swap to contiguous d-runs, store ----
  const float rl = 1.0f / l_i;
#pragma unroll
  for (int dt = 0; dt < 2; ++dt) {
    float s[16];
#pragma unroll
    for (int r = 0; r < 16; ++r) s[r] = o[dt][r] * rl;
    uint32_t u[8];
#pragma unroll
    for (int p = 0; p < 8; ++p)
      asm("v_cvt_pk_bf16_f32 %0, %1, %2" : "=v"(u[p]) : "v"(s[2 * p]), "v"(s[2 * p + 1]));
    asm("v_permlane32_swap_b32 %0, %1" : "+v"(u[0]), "+v"(u[2]));
    asm("v_permlane32_swap_b32 %0, %1" : "+v"(u[1]), "+v"(u[3]));
    asm("v_permlane32_swap_b32 %0, %1" : "+v"(u[4]), "+v"(u[6]));
    asm("v_permlane32_swap_b32 %0, %1" : "+v"(u[5]), "+v"(u[7]));
    unsigned short* op =
        ob + (size_t)(b * T_ + q0w + l31) * 1024 + h * 64 + dt * 32 + hi * 8;
    u32x4 c0 = {u[0], u[1], u[2], u[3]};   // d = dt*32 + hi*8 + [0..8)
    u32x4 c1 = {u[4], u[5], u[6], u[7]};   // d = dt*32 + 16 + hi*8 + [0..8)
    *(u32x4*)op = c0;
    *(u32x4*)(op + 16) = c1;
  }
}

// ---------------- host launch ----------------
extern "C" void kernel_launch(void* const* d_in, const int* in_sizes, int n_in,
                              void* d_out, int out_size, void* d_ws,
                              size_t ws_size, hipStream_t stream) {
  const float* x = (const float*)d_in[0];
  const float* Wq = (const float*)d_in[1];
  const float* Wk = (const float*)d_in[2];
  const float* Wv = (const float*)d_in[3];
  const float* Wo = (const float*)d_in[4];
  const float* bo = (const float*)d_in[5];
  float* out = (float*)d_out;

  // workspace layout (bytes)
  char* ws = (char*)d_ws;
  unsigned short* xb   = (unsigned short*)(ws + 0);          // 16 MB
  unsigned short* wqkv = (unsigned short*)(ws + 16777216);   // 6 MB
  unsigned short* wo   = (unsigned short*)(ws + 23068672);   // 2 MB
  unsigned short* qkv  = (unsigned short*)(ws + 25165824);   // 48 MB
  unsigned short* ob   = (unsigned short*)(ws + 75497472);   // 16 MB
  if (ws_size < 92274688u) return;

  // convert inputs to bf16 (concat Wq/Wk/Wv rows)
  cvt_kernel<<<8192, 256, 0, stream>>>(x, xb, 2097152);
  cvt_kernel<<<1024, 256, 0, stream>>>(Wq, wqkv, 262144);
  cvt_kernel<<<1024, 256, 0, stream>>>(Wk, wqkv + 1048576, 262144);
  cvt_kernel<<<1024, 256, 0, stream>>>(Wv, wqkv + 2097152, 262144);
  cvt_kernel<<<1024, 256, 0, stream>>>(Wo, wo, 262144);

  // fused QKV projection (Q cols pre-scaled by QSC in epilogue)
  gemm_bt<0><<<dim3(NQKV / 128, MTOT / 128), 256, 0, stream>>>(
      xb, wqkv, qkv, nullptr, nullptr, 1024, NQKV);

  // causal flash attention
  attn_kernel<<<dim3(512), 512, 0, stream>>>(qkv, ob);

  // output projection + bias: [8192 x 1024] f32
  gemm_bt<1><<<dim3(1024 / 128, MTOT / 128), 256, 0, stream>>>(
      ob, wo, nullptr, out, bo, 1024, 1024);
}

// Round 3
// 197.499 us; speedup vs baseline: 1.9690x; 1.0530x over previous
//
#include <hip/hip_runtime.h>
#include <hip/hip_bf16.h>
#include <stdint.h>

// Problem constants
#define B_   4
#define T_   2048
#define H_   16
#define MTOT (B_ * T_)          // 8192 rows
#define NQKV 3072               // fused QKV output cols
#define QSC  0.18033688f        // 0.125 * log2(e): fold softmax scale + exp2 conversion into Q

typedef __attribute__((ext_vector_type(8))) __bf16 bf16x8;
typedef __attribute__((ext_vector_type(4))) float f32x4;
typedef __attribute__((ext_vector_type(16))) float f32x16;
typedef __attribute__((ext_vector_type(4))) float f4v;
typedef __attribute__((ext_vector_type(4))) unsigned short us4;
typedef __attribute__((ext_vector_type(8))) unsigned short us8;
typedef __attribute__((ext_vector_type(4))) unsigned int u32x4;

static __device__ __forceinline__ unsigned short f2bf(float f) {
  __hip_bfloat16 h = __float2bfloat16(f);
  return __builtin_bit_cast(unsigned short, h);
}

static __device__ __forceinline__ void async16(const void* g, void* l) {
  __builtin_amdgcn_global_load_lds(
      (const __attribute__((address_space(1))) void*)g,
      (__attribute__((address_space(3))) void*)l, 16, 0, 0);
}

// ---------------- fused fp32 -> bf16 convert (x4 vectorized, 1 launch) --------
__global__ __launch_bounds__(256) void cvt_all(
    const float* __restrict__ x, const float* __restrict__ Wq,
    const float* __restrict__ Wk, const float* __restrict__ Wv,
    const float* __restrict__ Wo, unsigned short* __restrict__ xb,
    unsigned short* __restrict__ wqkv, unsigned short* __restrict__ wo) {
  int i = blockIdx.x * blockDim.x + threadIdx.x;
  const float* s; unsigned short* d; int j;
  if (i < 2097152)      { s = x;  d = xb;             j = i; }
  else if (i < 2359296) { s = Wq; d = wqkv;           j = i - 2097152; }
  else if (i < 2621440) { s = Wk; d = wqkv + 1048576; j = i - 2359296; }
  else if (i < 2883584) { s = Wv; d = wqkv + 2097152; j = i - 2621440; }
  else                  { s = Wo; d = wo;             j = i - 2883584; }
  f4v v = reinterpret_cast<const f4v*>(s)[j];
  us4 o;
  o.x = f2bf(v.x); o.y = f2bf(v.y); o.z = f2bf(v.z); o.w = f2bf(v.w);
  reinterpret_cast<us4*>(d)[j] = o;
}

// ---------------- bf16 GEMM, C = A * B^T (both stored K-major) ----------------
// MODE 0: bf16 output, cols < 1024 (Q) scaled by QSC.  MODE 1: f32 output + bias.
template <int MODE>
__global__ __launch_bounds__(256) void gemm_bt(
    const unsigned short* __restrict__ A,   // [M][K] bf16 bits
    const unsigned short* __restrict__ Bw,  // [N][K] bf16 bits
    unsigned short* __restrict__ Cb,        // bf16 out (MODE 0)
    float* __restrict__ Cf,                 // f32 out (MODE 1)
    const float* __restrict__ bias,         // MODE 1
    int K, int N) {
  __shared__ __align__(16) unsigned short As[128 * 32];
  __shared__ __align__(16) unsigned short Bs[128 * 32];

  const int t = threadIdx.x;
  const int lane = t & 63;
  const int w = t >> 6;
  const int lr = lane & 15;
  const int lg = lane >> 4;
  const int wm = w >> 1;
  const int wn = w & 1;
  const int m0 = blockIdx.y * 128;
  const int n0 = blockIdx.x * 128;

  f32x4 acc[4][4];
#pragma unroll
  for (int i = 0; i < 4; ++i)
#pragma unroll
    for (int j = 0; j < 4; ++j) acc[i][j] = (f32x4){0.f, 0.f, 0.f, 0.f};

  const int srow = t >> 2;          // 0..63
  const int scol = (t & 3) * 8;     // 0,8,16,24 elems
  const unsigned short* ga = A + (size_t)(m0 + srow) * K + scol;
  const unsigned short* gb = Bw + (size_t)(n0 + srow) * K + scol;

  for (int k0 = 0; k0 < K; k0 += 32) {
    async16(ga + k0,                  &As[t * 8]);
    async16(ga + k0 + (size_t)64 * K, &As[2048 + t * 8]);
    async16(gb + k0,                  &Bs[t * 8]);
    async16(gb + k0 + (size_t)64 * K, &Bs[2048 + t * 8]);
    __syncthreads();

    bf16x8 af[4], bfr[4];
#pragma unroll
    for (int mi = 0; mi < 4; ++mi)
      af[mi] = *(const bf16x8*)&As[(wm * 64 + mi * 16 + lr) * 32 + lg * 8];
#pragma unroll
    for (int ni = 0; ni < 4; ++ni)
      bfr[ni] = *(const bf16x8*)&Bs[(wn * 64 + ni * 16 + lr) * 32 + lg * 8];
#pragma unroll
    for (int mi = 0; mi < 4; ++mi)
#pragma unroll
      for (int ni = 0; ni < 4; ++ni)
        acc[mi][ni] = __builtin_amdgcn_mfma_f32_16x16x32_bf16(
            af[mi], bfr[ni], acc[mi][ni], 0, 0, 0);
    __syncthreads();
  }

  // epilogue: D layout col=lane&15, row=(lane>>4)*4+r
#pragma unroll
  for (int mi = 0; mi < 4; ++mi) {
    const int row = m0 + wm * 64 + mi * 16 + lg * 4;
#pragma unroll
    for (int ni = 0; ni < 4; ++ni) {
      const int col = n0 + wn * 64 + ni * 16 + lr;
#pragma unroll
      for (int r = 0; r < 4; ++r) {
        if (MODE == 1) {
          Cf[(size_t)(row + r) * N + col] = acc[mi][ni][r] + bias[col];
        } else {
          float v = acc[mi][ni][r];
          if (col < 1024) v *= QSC;   // pre-scale Q for exp2-space softmax
          Cb[(size_t)(row + r) * N + col] = f2bf(v);
        }
      }
    }
  }
}

// ---------------- causal flash attention (8 waves x 32 q-rows, 32x32 MFMA) ----
// qkv: [8192][3072] bf16 (cols: 0..1023 Q (pre-scaled), 1024..2047 K, 2048..3071 V)
// ob : [8192][1024] bf16 attention output (col = h*64+d)
//
// Swapped-operand scheme: S^T = K·Q^T via mfma(A=K, B=Q) -> lane owns q-col
// (lane&31); softmax fully in-register (tree-reduced, defer-max THR=8);
// P redistributed via cvt_pk + v_permlane32_swap_b32; O^T = V^T·P^T.
// KVBLK=128 staging (double-buffered), compute in 64-row halves.
__global__ __launch_bounds__(512, 2) void attn_kernel(
    const unsigned short* __restrict__ qkv, unsigned short* __restrict__ ob) {
  const int bid = blockIdx.x;
  const int qg = 7 - (bid >> 6);      // longest blocks dispatch first
  const int pair = bid & 63;
  const int b = pair >> 4;
  const int h = pair & 15;
  const int t = threadIdx.x;
  const int w = t >> 6;
  const int lane = t & 63;
  const int l31 = lane & 31;
  const int hi = lane >> 5;

  const int q0w = qg * 256 + w * 32;      // wave's q strip
  const int myBound = qg * 4 + (w >> 1);  // last 64-row kv-tile this wave computes
  const int NT2 = qg * 2 + 2;             // 128-row kv tiles staged by block

  __shared__ __align__(16) unsigned short Ks[2][128 * 64];  // K rows, chunk-swizzled
  __shared__ __align__(16) unsigned short Vs[2][128 * 64];  // V^T [64 d][128 kv], swizzled

  const size_t rowbase = (size_t)(b * T_) * NQKV;

  // ---- Q B-fragments (held all loop): col=q=l31, k=d = m*16 + hi*8 + i ----
  bf16x8 Qf[4];
  {
    const unsigned short* qp =
        qkv + rowbase + (size_t)(q0w + l31) * NQKV + h * 64 + hi * 8;
#pragma unroll
    for (int m = 0; m < 4; ++m) Qf[m] = *(const bf16x8*)(qp + m * 16);
  }

  // ---- staging geometry ----
  const int krow = t >> 3;                    // 0..63 (and +64 second half)
  const int kg = (t & 7) ^ (krow & 7);        // XOR-swizzled d-chunk
  const unsigned short* kbase =
      qkv + rowbase + 1024 + h * 64 + kg * 8 + (size_t)krow * NQKV;
  const int kvr = t >> 3;
  const int dc = t & 7;
  const unsigned short* vbase =
      qkv + rowbase + 2048 + h * 64 + dc * 8 + (size_t)kvr * NQKV;

  float m_i = -INFINITY, l_i = 0.f;
  f32x16 o[2];
#pragma unroll
  for (int r = 0; r < 16; ++r) { o[0][r] = 0.f; o[1][r] = 0.f; }

  // V scatter-transpose: elem(d, kv) -> Vs[d*128 + ((kv>>3) ^ (d>>3) ^ (d&7))*8 + (kv&7)]
  // (XOR of 3-bit value keeps kv-halves separated: chunks 0..7 / 8..15)
#define VSCATTER(Vb, v0, v1)                                     \
  {                                                              \
    _Pragma("unroll") for (int i = 0; i < 8; ++i) {              \
      const int sw = dc ^ i;                                     \
      const int c0 = (kvr >> 3) ^ sw;                            \
      unsigned short* vp = (Vb) + (dc * 8 + i) * 128 + (kvr & 7);\
      vp[c0 * 8] = (v0)[i];                                      \
      vp[(c0 ^ 8 ^ 8) * 8 + 64] = (v1)[i];                       \
    }                                                            \
  }

  // ---- prologue: stage tile 0 into buffer 0 ----
  {
    async16(kbase, &Ks[0][t * 8]);
    async16(kbase + (size_t)64 * NQKV, &Ks[0][4096 + t * 8]);
    us8 v0 = *(const us8*)vbase;
    us8 v1 = *(const us8*)(vbase + (size_t)64 * NQKV);
    VSCATTER(&Vs[0][0], v0, v1);
  }

  int cur = 0;
  for (int kt = 0; kt < NT2; ++kt) {
    __syncthreads();  // buf[cur] ready (drains async K + V ds_writes)

    const bool pf = (kt + 1 < NT2);
    us8 v0, v1;
    if (pf) {
      const size_t off = (size_t)(kt + 1) * 128 * NQKV;
      async16(kbase + off, &Ks[cur ^ 1][t * 8]);
      async16(kbase + off + (size_t)64 * NQKV, &Ks[cur ^ 1][4096 + t * 8]);
      v0 = *(const us8*)(vbase + off);
      v1 = *(const us8*)(vbase + off + (size_t)64 * NQKV);
    }

    const unsigned short* Kb = Ks[cur];
    const unsigned short* Vb = Vs[cur];

#pragma unroll
    for (int kh = 0; kh < 2; ++kh) {
      const int kt64 = kt * 2 + kh;
      if (kt64 > myBound) break;  // wave-uniform

      // ---- S^T[kv][q] : 2 kv-subtiles of 32 ----
      f32x16 a0, a1;
#pragma unroll
      for (int r = 0; r < 16; ++r) { a0[r] = 0.f; a1[r] = 0.f; }
      {
        const int rb0 = (kh * 64 + l31) * 64;
        const int rb1 = (kh * 64 + 32 + l31) * 64;
        const int r7 = l31 & 7;
        __builtin_amdgcn_s_setprio(1);
#pragma unroll
        for (int m = 0; m < 4; ++m) {
          const int c = (((m << 1) | hi) ^ r7) * 8;
          bf16x8 kf0 = *(const bf16x8*)&Kb[rb0 + c];
          bf16x8 kf1 = *(const bf16x8*)&Kb[rb1 + c];
          a0 = __builtin_amdgcn_mfma_f32_32x32x16_bf16(kf0, Qf[m], a0, 0, 0, 0);
          a1 = __builtin_amdgcn_mfma_f32_32x32x16_bf16(kf1, Qf[m], a1, 0, 0, 0);
        }
        __builtin_amdgcn_s_setprio(0);
      }

      // ---- causal mask: only the diagonal-crossing tile ----
      if (kt64 == myBound) {
        const int qglob = q0w + l31;
#pragma unroll
        for (int r = 0; r < 16; ++r) {
          const int kvb = kt64 * 64 + (r & 3) + ((r >> 2) << 3) + (hi << 2);
          if (kvb > qglob) a0[r] = -INFINITY;
          if (kvb + 32 > qglob) a1[r] = -INFINITY;
        }
      }

      // ---- online softmax: tree max, defer-max (THR=8 in log2 space) ----
      float m8[8];
#pragma unroll
      for (int j = 0; j < 8; ++j)
        m8[j] = fmaxf(fmaxf(a0[j], a0[j + 8]), fmaxf(a1[j], a1[j + 8]));
      float pmax = fmaxf(fmaxf(fmaxf(m8[0], m8[4]), fmaxf(m8[1], m8[5])),
                         fmaxf(fmaxf(m8[2], m8[6]), fmaxf(m8[3], m8[7])));
      pmax = fmaxf(pmax, __shfl_xor(pmax, 32));
      if (__any(pmax > m_i + 8.f)) {
        const float mnew = fmaxf(m_i, pmax);
        const float al = exp2f(m_i - mnew);
        m_i = mnew;
        l_i *= al;
#pragma unroll
        for (int r = 0; r < 16; ++r) { o[0][r] *= al; o[1][r] *= al; }
      }

#pragma unroll
      for (int r = 0; r < 16; ++r) {
        a0[r] = exp2f(a0[r] - m_i);
        a1[r] = exp2f(a1[r] - m_i);
      }
      float s8[8];
#pragma unroll
      for (int j = 0; j < 8; ++j)
        s8[j] = (a0[j] + a0[j + 8]) + (a1[j] + a1[j + 8]);
      float rs = ((s8[0] + s8[1]) + (s8[2] + s8[3])) +
                 ((s8[4] + s8[5]) + (s8[6] + s8[7]));
      rs += __shfl_xor(rs, 32);
      l_i += rs;

      // ---- P^T B-fragments: cvt_pk pairs + permlane32_swap half-exchange ----
      bf16x8 Pf[4];
#pragma unroll
      for (int m = 0; m < 4; ++m) {
        const int rb2 = (m & 1) * 8;
        uint32_t u0, u1, u2, u3;
        const f32x16& s = (m >> 1) ? a1 : a0;
        asm("v_cvt_pk_bf16_f32 %0, %1, %2" : "=v"(u0) : "v"(s[rb2 + 0]), "v"(s[rb2 + 1]));
        asm("v_cvt_pk_bf16_f32 %0, %1, %2" : "=v"(u1) : "v"(s[rb2 + 2]), "v"(s[rb2 + 3]));
        asm("v_cvt_pk_bf16_f32 %0, %1, %2" : "=v"(u2) : "v"(s[rb2 + 4]), "v"(s[rb2 + 5]));
        asm("v_cvt_pk_bf16_f32 %0, %1, %2" : "=v"(u3) : "v"(s[rb2 + 6]), "v"(s[rb2 + 7]));
        asm("v_permlane32_swap_b32 %0, %1" : "+v"(u0), "+v"(u2));
        asm("v_permlane32_swap_b32 %0, %1" : "+v"(u1), "+v"(u3));
        u32x4 pw = {u0, u1, u2, u3};
        Pf[m] = __builtin_bit_cast(bf16x8, pw);
      }

      // ---- O^T += V^T P^T ----
      __builtin_amdgcn_s_setprio(1);
#pragma unroll
      for (int dt = 0; dt < 2; ++dt) {
        const int d = dt * 32 + l31;
        const int base = d * 128 + kh * 64;
        const int dsw = ((d >> 3) ^ d) & 7;
#pragma unroll
        for (int m = 0; m < 4; ++m) {
          bf16x8 vf = *(const bf16x8*)&Vb[base + ((((m << 1) | hi) ^ dsw) & 7) * 8];
          o[dt] = __builtin_amdgcn_mfma_f32_32x32x16_bf16(vf, Pf[m], o[dt], 0, 0, 0);
        }
      }
      __builtin_amdgcn_s_setprio(0);
    }

    if (pf) VSCATTER(&Vs[cur ^ 1][0], v0, v1);
    cur ^= 1;
  }

  // ---- epilogue: normalize, pack to bf16, swap to contiguous d-runs, store ----
  const float rl = 1.0f / l_i;
#pragma unroll
  for (int dt = 0; dt < 2; ++dt) {
    float s[16];
#pragma unroll
    for (int r = 0; r < 16; ++r) s[r] = o[dt][r] * rl;
    uint32_t u[8];
#pragma unroll
    for (int p = 0; p < 8; ++p)
      asm("v_cvt_pk_bf16_f32 %0, %1, %2" : "=v"(u[p]) : "v"(s[2 * p]), "v"(s[2 * p + 1]));
    asm("v_permlane32_swap_b32 %0, %1" : "+v"(u[0]), "+v"(u[2]));
    asm("v_permlane32_swap_b32 %0, %1" : "+v"(u[1]), "+v"(u[3]));
    asm("v_permlane32_swap_b32 %0, %1" : "+v"(u[4]), "+v"(u[6]));
    asm("v_permlane32_swap_b32 %0, %1" : "+v"(u[5]), "+v"(u[7]));
    unsigned short* op =
        ob + (size_t)(b * T_ + q0w + l31) * 1024 + h * 64 + dt * 32 + hi * 8;
    u32x4 c0 = {u[0], u[1], u[2], u[3]};   // d = dt*32 + hi*8 + [0..8)
    u32x4 c1 = {u[4], u[5], u[6], u[7]};   // d = dt*32 + 16 + hi*8 + [0..8)
    *(u32x4*)op = c0;
    *(u32x4*)(op + 16) = c1;
  }
}

// ---------------- host launch ----------------
extern "C" void kernel_launch(void* const* d_in, const int* in_sizes, int n_in,
                              void* d_out, int out_size, void* d_ws,
                              size_t ws_size, hipStream_t stream) {
  const float* x = (const float*)d_in[0];
  const float* Wq = (const float*)d_in[1];
  const float* Wk = (const float*)d_in[2];
  const float* Wv = (const float*)d_in[3];
  const float* Wo = (const float*)d_in[4];
  const float* bo = (const float*)d_in[5];
  float* out = (float*)d_out;

  // workspace layout (bytes)
  char* ws = (char*)d_ws;
  unsigned short* xb   = (unsigned short*)(ws + 0);          // 16 MB
  unsigned short* wqkv = (unsigned short*)(ws + 16777216);   // 6 MB
  unsigned short* wo   = (unsigned short*)(ws + 23068672);   // 2 MB
  unsigned short* qkv  = (unsigned short*)(ws + 25165824);   // 48 MB
  unsigned short* ob   = (unsigned short*)(ws + 75497472);   // 16 MB
  if (ws_size < 92274688u) return;

  // convert all inputs to bf16 in one launch (concat Wq/Wk/Wv rows)
  cvt_all<<<12288, 256, 0, stream>>>(x, Wq, Wk, Wv, Wo, xb, wqkv, wo);

  // fused QKV projection (Q cols pre-scaled by QSC in epilogue)
  gemm_bt<0><<<dim3(NQKV / 128, MTOT / 128), 256, 0, stream>>>(
      xb, wqkv, qkv, nullptr, nullptr, 1024, NQKV);

  // causal flash attention
  attn_kernel<<<dim3(512), 512, 0, stream>>>(qkv, ob);

  // output projection + bias: [8192 x 1024] f32
  gemm_bt<1><<<dim3(1024 / 128, MTOT / 128), 256, 0, stream>>>(
      ob, wo, nullptr, out, bo, 1024, 1024);
}

// Round 4
// 190.715 us; speedup vs baseline: 2.0390x; 1.0356x over previous
//
#include <hip/hip_runtime.h>
#include <hip/hip_bf16.h>
#include <stdint.h>

// Problem constants
#define B_   4
#define T_   2048
#define H_   16
#define MTOT (B_ * T_)          // 8192 rows
#define NQKV 3072               // fused QKV output cols
#define QSC  0.18033688f        // 0.125 * log2(e): fold softmax scale + exp2 conversion into Q

typedef __attribute__((ext_vector_type(8))) __bf16 bf16x8;
typedef __attribute__((ext_vector_type(4))) float f32x4;
typedef __attribute__((ext_vector_type(16))) float f32x16;
typedef __attribute__((ext_vector_type(4))) float f4v;
typedef __attribute__((ext_vector_type(4))) unsigned short us4;
typedef __attribute__((ext_vector_type(8))) unsigned short us8;
typedef __attribute__((ext_vector_type(4))) unsigned int u32x4;

static __device__ __forceinline__ unsigned short f2bf(float f) {
  __hip_bfloat16 h = __float2bfloat16(f);
  return __builtin_bit_cast(unsigned short, h);
}

static __device__ __forceinline__ float fast_exp2(float x) {
#if __has_builtin(__builtin_amdgcn_exp2f)
  return __builtin_amdgcn_exp2f(x);
#else
  float r; asm("v_exp_f32 %0, %1" : "=v"(r) : "v"(x)); return r;
#endif
}

static __device__ __forceinline__ void async16(const void* g, void* l) {
  __builtin_amdgcn_global_load_lds(
      (const __attribute__((address_space(1))) void*)g,
      (__attribute__((address_space(3))) void*)l, 16, 0, 0);
}

#define VMWAIT(n) asm volatile("s_waitcnt vmcnt(" #n ")" ::: "memory")
#define SB0() __builtin_amdgcn_sched_barrier(0)

// ---------------- fused fp32 -> bf16 convert (x4 vectorized, 1 launch) --------
__global__ __launch_bounds__(256) void cvt_all(
    const float* __restrict__ x, const float* __restrict__ Wq,
    const float* __restrict__ Wk, const float* __restrict__ Wv,
    const float* __restrict__ Wo, unsigned short* __restrict__ xb,
    unsigned short* __restrict__ wqkv, unsigned short* __restrict__ wo) {
  int i = blockIdx.x * blockDim.x + threadIdx.x;
  const float* s; unsigned short* d; int j;
  if (i < 2097152)      { s = x;  d = xb;             j = i; }
  else if (i < 2359296) { s = Wq; d = wqkv;           j = i - 2097152; }
  else if (i < 2621440) { s = Wk; d = wqkv + 1048576; j = i - 2359296; }
  else if (i < 2883584) { s = Wv; d = wqkv + 2097152; j = i - 2621440; }
  else                  { s = Wo; d = wo;             j = i - 2883584; }
  f4v v = reinterpret_cast<const f4v*>(s)[j];
  us4 o;
  o.x = f2bf(v.x); o.y = f2bf(v.y); o.z = f2bf(v.z); o.w = f2bf(v.w);
  reinterpret_cast<us4*>(d)[j] = o;
}

// ---------------- 8-phase counted-vmcnt GEMM: qkv = xb * wqkv^T ---------------
// BM=128, BN=256, BK=64 (2 K-chunks of 32), 512 threads = 8 waves (2M x 4N),
// wave computes 64x64 (4x4 16x16 frags). LDS K-split halves (wave-uniform
// need schedule), swizzle slot = chunk ^ ((row>>1)&3) (2-way max on reads),
// applied via pre-swizzled global source (linear gload_lds dest).
// Per tile: 4 phases, each {stage 1 half | counted vmcnt | barrier | ds_read |
// 8 MFMA (setprio)}. Steady-state vmcnt(4) - never drains in main loop.
__global__ __launch_bounds__(512, 2) void gemm256(
    const unsigned short* __restrict__ A,   // [8192][1024]
    const unsigned short* __restrict__ Bw,  // [3072][1024]
    unsigned short* __restrict__ Cb) {      // [8192][3072], Q cols scaled
  const int K = 1024;
  __shared__ __align__(16) unsigned short Al[2][2][128 * 32];
  __shared__ __align__(16) unsigned short Bl[2][2][256 * 32];

  // XCD-bijective swizzle over 768 blocks (768 % 8 == 0), m-major per chunk
  const int bid0 = blockIdx.x;
  const int bid = (bid0 & 7) * 96 + (bid0 >> 3);
  const int m0 = (bid & 63) * 128;
  const int n0 = (bid >> 6) * 256;

  const int t = threadIdx.x;
  const int lane = t & 63;
  const int w = t >> 6;
  const int lr = lane & 15;
  const int lg = lane >> 4;
  const int wm = w >> 2;       // 0..1
  const int wn = w & 3;        // 0..3

  // staging sources (pre-swizzled: LDS slot s at row r holds chunk s^((r>>1)&3))
  const int ra = t >> 2, sa = t & 3;
  const unsigned short* srcA =
      A + (size_t)(m0 + ra) * K + (sa ^ ((ra >> 1) & 3)) * 8;
  const int rb1 = 128 + (t >> 2);
  const unsigned short* srcB0 =
      Bw + (size_t)(n0 + ra) * K + (sa ^ ((ra >> 1) & 3)) * 8;
  const unsigned short* srcB1 =
      Bw + (size_t)(n0 + rb1) * K + (sa ^ ((rb1 >> 1) & 3)) * 8;

  const int aslot8 = (lg ^ ((lr >> 1) & 3)) * 8;   // same for A and B reads

  f32x4 acc[4][4];
#pragma unroll
  for (int i = 0; i < 4; ++i)
#pragma unroll
    for (int j = 0; j < 4; ++j) acc[i][j] = (f32x4){0.f, 0.f, 0.f, 0.f};

#define STAGE_A(bufi, kc, koff) \
  async16(srcA + (koff) + (kc) * 32, &Al[bufi][kc][t * 8])
#define STAGE_B(bufi, kc, koff)                                  \
  do {                                                           \
    async16(srcB0 + (koff) + (kc) * 32, &Bl[bufi][kc][t * 8]);   \
    async16(srcB1 + (koff) + (kc) * 32, &Bl[bufi][kc][4096 + t * 8]); \
  } while (0)
#define READS_A(cur, kc)                                                   \
  _Pragma("unroll") for (int mi = 0; mi < 4; ++mi)                         \
      af[mi] = *(const bf16x8*)&Al[cur][kc][(wm * 64 + mi * 16 + lr) * 32 + aslot8];
#define READS_B(cur, kc, nh)                                               \
  _Pragma("unroll") for (int nj = 0; nj < 2; ++nj)                         \
      bfr[nj] = *(const bf16x8*)&Bl[cur][kc][(wn * 64 + (nh) * 32 + nj * 16 + lr) * 32 + aslot8];
#define PH_MFMA(kc, nh)                                                    \
  __builtin_amdgcn_s_setprio(1);                                           \
  _Pragma("unroll") for (int mi = 0; mi < 4; ++mi)                         \
      _Pragma("unroll") for (int nj = 0; nj < 2; ++nj)                     \
          acc[mi][(nh) * 2 + nj] = __builtin_amdgcn_mfma_f32_16x16x32_bf16( \
              af[mi], bfr[nj], acc[mi][(nh) * 2 + nj], 0, 0, 0);           \
  __builtin_amdgcn_s_setprio(0);

  bf16x8 af[4], bfr[2];

  // prologue: stage tile 0 into buf 0 (load order per tile: A0, B0, A1, B1)
  STAGE_A(0, 0, 0);
  STAGE_B(0, 0, 0);
  STAGE_A(0, 1, 0);
  STAGE_B(0, 1, 0);

  for (int kt = 0; kt < 15; ++kt) {
    const int cur = kt & 1, nxt = cur ^ 1;
    const int ko = kt * 64 + 64;
    // ---- ph0: compute (kc0, nh0); stage next A0 ----
    STAGE_A(nxt, 0, ko);
    VMWAIT(4);                     // this tile's A0,B0 landed (all older too)
    SB0();
    __builtin_amdgcn_s_barrier();  // -> landed for ALL waves
    SB0();
    READS_A(cur, 0);
    READS_B(cur, 0, 0);
    PH_MFMA(0, 0);
    // ---- ph1: (kc0, nh1); stage next B0 ----
    STAGE_B(nxt, 0, ko);
    SB0();
    __builtin_amdgcn_s_barrier();
    SB0();
    READS_B(cur, 0, 1);
    PH_MFMA(0, 1);
    // ---- ph2: (kc1, nh0); stage next A1 ----
    STAGE_A(nxt, 1, ko);
    VMWAIT(4);                     // this tile's A1,B1 landed
    SB0();
    __builtin_amdgcn_s_barrier();
    SB0();
    READS_A(cur, 1);
    READS_B(cur, 1, 0);
    PH_MFMA(1, 0);
    // ---- ph3: (kc1, nh1); stage next B1 ----
    STAGE_B(nxt, 1, ko);
    SB0();
    __builtin_amdgcn_s_barrier();
    SB0();
    READS_B(cur, 1, 1);
    PH_MFMA(1, 1);
  }
  {  // peeled last tile (kt=15, cur=1): no staging, drain allowed
    VMWAIT(3);                     // A0,B0 of tile 15 landed
    SB0();
    __builtin_amdgcn_s_barrier();
    SB0();
    READS_A(1, 0);
    READS_B(1, 0, 0);
    PH_MFMA(0, 0);
    READS_B(1, 0, 1);
    PH_MFMA(0, 1);
    VMWAIT(0);
    SB0();
    __builtin_amdgcn_s_barrier();
    SB0();
    READS_A(1, 1);
    READS_B(1, 1, 0);
    PH_MFMA(1, 0);
    READS_B(1, 1, 1);
    PH_MFMA(1, 1);
  }

  // epilogue: D layout col=lane&15, row=(lane>>4)*4+r ; Q cols scaled by QSC
#pragma unroll
  for (int mi = 0; mi < 4; ++mi) {
    const int row = m0 + wm * 64 + mi * 16 + lg * 4;
#pragma unroll
    for (int ni = 0; ni < 4; ++ni) {
      const int col = n0 + wn * 64 + ni * 16 + lr;
      const float sc = (col < 1024) ? QSC : 1.0f;
#pragma unroll
      for (int r = 0; r < 4; ++r)
        Cb[(size_t)(row + r) * NQKV + col] = f2bf(acc[mi][ni][r] * sc);
    }
  }
#undef STAGE_A
#undef STAGE_B
#undef READS_A
#undef READS_B
#undef PH_MFMA
}

// ---------------- bf16 GEMM (m97 structure), C = A * B^T, f32 out + bias -----
__global__ __launch_bounds__(256) void gemm_bt(
    const unsigned short* __restrict__ A,   // [M][K] bf16 bits
    const unsigned short* __restrict__ Bw,  // [N][K] bf16 bits
    float* __restrict__ Cf,                 // f32 out
    const float* __restrict__ bias,
    int K, int N) {
  __shared__ __align__(16) unsigned short As[128 * 32];
  __shared__ __align__(16) unsigned short Bs[128 * 32];

  const int t = threadIdx.x;
  const int lane = t & 63;
  const int w = t >> 6;
  const int lr = lane & 15;
  const int lg = lane >> 4;
  const int wm = w >> 1;
  const int wn = w & 1;
  const int m0 = blockIdx.y * 128;
  const int n0 = blockIdx.x * 128;

  f32x4 acc[4][4];
#pragma unroll
  for (int i = 0; i < 4; ++i)
#pragma unroll
    for (int j = 0; j < 4; ++j) acc[i][j] = (f32x4){0.f, 0.f, 0.f, 0.f};

  const int srow = t >> 2;
  const int scol = (t & 3) * 8;
  const unsigned short* ga = A + (size_t)(m0 + srow) * K + scol;
  const unsigned short* gb = Bw + (size_t)(n0 + srow) * K + scol;

  for (int k0 = 0; k0 < K; k0 += 32) {
    async16(ga + k0,                  &As[t * 8]);
    async16(ga + k0 + (size_t)64 * K, &As[2048 + t * 8]);
    async16(gb + k0,                  &Bs[t * 8]);
    async16(gb + k0 + (size_t)64 * K, &Bs[2048 + t * 8]);
    __syncthreads();

    bf16x8 af[4], bfr[4];
#pragma unroll
    for (int mi = 0; mi < 4; ++mi)
      af[mi] = *(const bf16x8*)&As[(wm * 64 + mi * 16 + lr) * 32 + lg * 8];
#pragma unroll
    for (int ni = 0; ni < 4; ++ni)
      bfr[ni] = *(const bf16x8*)&Bs[(wn * 64 + ni * 16 + lr) * 32 + lg * 8];
#pragma unroll
    for (int mi = 0; mi < 4; ++mi)
#pragma unroll
      for (int ni = 0; ni < 4; ++ni)
        acc[mi][ni] = __builtin_amdgcn_mfma_f32_16x16x32_bf16(
            af[mi], bfr[ni], acc[mi][ni], 0, 0, 0);
    __syncthreads();
  }

#pragma unroll
  for (int mi = 0; mi < 4; ++mi) {
    const int row = m0 + wm * 64 + mi * 16 + lg * 4;
#pragma unroll
    for (int ni = 0; ni < 4; ++ni) {
      const int col = n0 + wn * 64 + ni * 16 + lr;
#pragma unroll
      for (int r = 0; r < 4; ++r)
        Cf[(size_t)(row + r) * N + col] = acc[mi][ni][r] + bias[col];
    }
  }
}

// ---------------- causal flash attention (8 waves x 32 q-rows, 32x32 MFMA) ----
__global__ __launch_bounds__(512, 2) void attn_kernel(
    const unsigned short* __restrict__ qkv, unsigned short* __restrict__ ob) {
  const int bid = blockIdx.x;
  const int qg = 7 - (bid >> 6);      // longest blocks dispatch first
  const int pair = bid & 63;
  const int b = pair >> 4;
  const int h = pair & 15;
  const int t = threadIdx.x;
  const int w = t >> 6;
  const int lane = t & 63;
  const int l31 = lane & 31;
  const int hi = lane >> 5;

  const int q0w = qg * 256 + w * 32;
  const int myBound = qg * 4 + (w >> 1);
  const int NT2 = qg * 2 + 2;

  __shared__ __align__(16) unsigned short Ks[2][128 * 64];
  __shared__ __align__(16) unsigned short Vs[2][128 * 64];

  const size_t rowbase = (size_t)(b * T_) * NQKV;

  bf16x8 Qf[4];
  {
    const unsigned short* qp =
        qkv + rowbase + (size_t)(q0w + l31) * NQKV + h * 64 + hi * 8;
#pragma unroll
    for (int m = 0; m < 4; ++m) Qf[m] = *(const bf16x8*)(qp + m * 16);
  }

  const int krow = t >> 3;
  const int kg = (t & 7) ^ (krow & 7);
  const unsigned short* kbase =
      qkv + rowbase + 1024 + h * 64 + kg * 8 + (size_t)krow * NQKV;
  const int kvr = t >> 3;
  const int dc = t & 7;
  const unsigned short* vbase =
      qkv + rowbase + 2048 + h * 64 + dc * 8 + (size_t)kvr * NQKV;

  float m_i = -INFINITY, l_i = 0.f;
  f32x16 o[2];
#pragma unroll
  for (int r = 0; r < 16; ++r) { o[0][r] = 0.f; o[1][r] = 0.f; }

#define VSCATTER(Vb, v0, v1)                                     \
  {                                                              \
    _Pragma("unroll") for (int i = 0; i < 8; ++i) {              \
      const int sw = dc ^ i;                                     \
      const int c0 = (kvr >> 3) ^ sw;                            \
      unsigned short* vp = (Vb) + (dc * 8 + i) * 128 + (kvr & 7);\
      vp[c0 * 8] = (v0)[i];                                      \
      vp[c0 * 8 + 64] = (v1)[i];                                 \
    }                                                            \
  }

  {
    async16(kbase, &Ks[0][t * 8]);
    async16(kbase + (size_t)64 * NQKV, &Ks[0][4096 + t * 8]);
    us8 v0 = *(const us8*)vbase;
    us8 v1 = *(const us8*)(vbase + (size_t)64 * NQKV);
    VSCATTER(&Vs[0][0], v0, v1);
  }

  int cur = 0;
  for (int kt = 0; kt < NT2; ++kt) {
    __syncthreads();

    const bool pf = (kt + 1 < NT2);
    us8 v0, v1;
    if (pf) {
      const size_t off = (size_t)(kt + 1) * 128 * NQKV;
      async16(kbase + off, &Ks[cur ^ 1][t * 8]);
      async16(kbase + off + (size_t)64 * NQKV, &Ks[cur ^ 1][4096 + t * 8]);
      v0 = *(const us8*)(vbase + off);
      v1 = *(const us8*)(vbase + off + (size_t)64 * NQKV);
    }

    const unsigned short* Kb = Ks[cur];
    const unsigned short* Vb = Vs[cur];

#pragma unroll
    for (int kh = 0; kh < 2; ++kh) {
      const int kt64 = kt * 2 + kh;
      if (kt64 > myBound) break;

      f32x16 a0, a1;
#pragma unroll
      for (int r = 0; r < 16; ++r) { a0[r] = 0.f; a1[r] = 0.f; }
      {
        const int rb0 = (kh * 64 + l31) * 64;
        const int rb1 = (kh * 64 + 32 + l31) * 64;
        const int r7 = l31 & 7;
        __builtin_amdgcn_s_setprio(1);
#pragma unroll
        for (int m = 0; m < 4; ++m) {
          const int c = (((m << 1) | hi) ^ r7) * 8;
          bf16x8 kf0 = *(const bf16x8*)&Kb[rb0 + c];
          bf16x8 kf1 = *(const bf16x8*)&Kb[rb1 + c];
          a0 = __builtin_amdgcn_mfma_f32_32x32x16_bf16(kf0, Qf[m], a0, 0, 0, 0);
          a1 = __builtin_amdgcn_mfma_f32_32x32x16_bf16(kf1, Qf[m], a1, 0, 0, 0);
        }
        __builtin_amdgcn_s_setprio(0);
      }

      if (kt64 == myBound) {
        const int qglob = q0w + l31;
#pragma unroll
        for (int r = 0; r < 16; ++r) {
          const int kvb = kt64 * 64 + (r & 3) + ((r >> 2) << 3) + (hi << 2);
          if (kvb > qglob) a0[r] = -INFINITY;
          if (kvb + 32 > qglob) a1[r] = -INFINITY;
        }
      }

      // online softmax: tree max, defer-max (THR=8 in log2 space)
      float m8[8];
#pragma unroll
      for (int j = 0; j < 8; ++j)
        m8[j] = fmaxf(fmaxf(a0[j], a0[j + 8]), fmaxf(a1[j], a1[j + 8]));
      float pmax = fmaxf(fmaxf(fmaxf(m8[0], m8[4]), fmaxf(m8[1], m8[5])),
                         fmaxf(fmaxf(m8[2], m8[6]), fmaxf(m8[3], m8[7])));
      pmax = fmaxf(pmax, __shfl_xor(pmax, 32));
      if (__any(pmax > m_i + 8.f)) {
        const float mnew = fmaxf(m_i, pmax);
        const float al = fast_exp2(m_i - mnew);
        m_i = mnew;
        l_i *= al;
#pragma unroll
        for (int r = 0; r < 16; ++r) { o[0][r] *= al; o[1][r] *= al; }
      }

#pragma unroll
      for (int r = 0; r < 16; ++r) {
        a0[r] = fast_exp2(a0[r] - m_i);
        a1[r] = fast_exp2(a1[r] - m_i);
      }
      float s8[8];
#pragma unroll
      for (int j = 0; j < 8; ++j)
        s8[j] = (a0[j] + a0[j + 8]) + (a1[j] + a1[j + 8]);
      float rs = ((s8[0] + s8[1]) + (s8[2] + s8[3])) +
                 ((s8[4] + s8[5]) + (s8[6] + s8[7]));
      rs += __shfl_xor(rs, 32);
      l_i += rs;

      bf16x8 Pf[4];
#pragma unroll
      for (int m = 0; m < 4; ++m) {
        const int rb2 = (m & 1) * 8;
        uint32_t u0, u1, u2, u3;
        const f32x16& s = (m >> 1) ? a1 : a0;
        asm("v_cvt_pk_bf16_f32 %0, %1, %2" : "=v"(u0) : "v"(s[rb2 + 0]), "v"(s[rb2 + 1]));
        asm("v_cvt_pk_bf16_f32 %0, %1, %2" : "=v"(u1) : "v"(s[rb2 + 2]), "v"(s[rb2 + 3]));
        asm("v_cvt_pk_bf16_f32 %0, %1, %2" : "=v"(u2) : "v"(s[rb2 + 4]), "v"(s[rb2 + 5]));
        asm("v_cvt_pk_bf16_f32 %0, %1, %2" : "=v"(u3) : "v"(s[rb2 + 6]), "v"(s[rb2 + 7]));
        asm("v_permlane32_swap_b32 %0, %1" : "+v"(u0), "+v"(u2));
        asm("v_permlane32_swap_b32 %0, %1" : "+v"(u1), "+v"(u3));
        u32x4 pw = {u0, u1, u2, u3};
        Pf[m] = __builtin_bit_cast(bf16x8, pw);
      }

      __builtin_amdgcn_s_setprio(1);
#pragma unroll
      for (int dt = 0; dt < 2; ++dt) {
        const int d = dt * 32 + l31;
        const int base = d * 128 + kh * 64;
        const int dsw = ((d >> 3) ^ d) & 7;
#pragma unroll
        for (int m = 0; m < 4; ++m) {
          bf16x8 vf = *(const bf16x8*)&Vb[base + ((((m << 1) | hi) ^ dsw) & 7) * 8];
          o[dt] = __builtin_amdgcn_mfma_f32_32x32x16_bf16(vf, Pf[m], o[dt], 0, 0, 0);
        }
      }
      __builtin_amdgcn_s_setprio(0);
    }

    if (pf) VSCATTER(&Vs[cur ^ 1][0], v0, v1);
    cur ^= 1;
  }

  const float rl = 1.0f / l_i;
#pragma unroll
  for (int dt = 0; dt < 2; ++dt) {
    float s[16];
#pragma unroll
    for (int r = 0; r < 16; ++r) s[r] = o[dt][r] * rl;
    uint32_t u[8];
#pragma unroll
    for (int p = 0; p < 8; ++p)
      asm("v_cvt_pk_bf16_f32 %0, %1, %2" : "=v"(u[p]) : "v"(s[2 * p]), "v"(s[2 * p + 1]));
    asm("v_permlane32_swap_b32 %0, %1" : "+v"(u[0]), "+v"(u[2]));
    asm("v_permlane32_swap_b32 %0, %1" : "+v"(u[1]), "+v"(u[3]));
    asm("v_permlane32_swap_b32 %0, %1" : "+v"(u[4]), "+v"(u[6]));
    asm("v_permlane32_swap_b32 %0, %1" : "+v"(u[5]), "+v"(u[7]));
    unsigned short* op =
        ob + (size_t)(b * T_ + q0w + l31) * 1024 + h * 64 + dt * 32 + hi * 8;
    u32x4 c0 = {u[0], u[1], u[2], u[3]};
    u32x4 c1 = {u[4], u[5], u[6], u[7]};
    *(u32x4*)op = c0;
    *(u32x4*)(op + 16) = c1;
  }
}

// ---------------- host launch ----------------
extern "C" void kernel_launch(void* const* d_in, const int* in_sizes, int n_in,
                              void* d_out, int out_size, void* d_ws,
                              size_t ws_size, hipStream_t stream) {
  const float* x = (const float*)d_in[0];
  const float* Wq = (const float*)d_in[1];
  const float* Wk = (const float*)d_in[2];
  const float* Wv = (const float*)d_in[3];
  const float* Wo = (const float*)d_in[4];
  const float* bo = (const float*)d_in[5];
  float* out = (float*)d_out;

  char* ws = (char*)d_ws;
  unsigned short* xb   = (unsigned short*)(ws + 0);          // 16 MB
  unsigned short* wqkv = (unsigned short*)(ws + 16777216);   // 6 MB
  unsigned short* wo   = (unsigned short*)(ws + 23068672);   // 2 MB
  unsigned short* qkv  = (unsigned short*)(ws + 25165824);   // 48 MB
  unsigned short* ob   = (unsigned short*)(ws + 75497472);   // 16 MB
  if (ws_size < 92274688u) return;

  cvt_all<<<12288, 256, 0, stream>>>(x, Wq, Wk, Wv, Wo, xb, wqkv, wo);

  // fused QKV projection: 8-phase counted-vmcnt GEMM (768 blocks = 3 CU rounds)
  gemm256<<<768, 512, 0, stream>>>(xb, wqkv, qkv);

  // causal flash attention
  attn_kernel<<<dim3(512), 512, 0, stream>>>(qkv, ob);

  // output projection + bias
  gemm_bt<<<dim3(1024 / 128, MTOT / 128), 256, 0, stream>>>(
      ob, wo, out, bo, 1024, 1024);
}

// Round 5
// 190.117 us; speedup vs baseline: 2.0454x; 1.0031x over previous
//
#include <hip/hip_runtime.h>
#include <hip/hip_bf16.h>
#include <stdint.h>

// Problem constants
#define B_   4
#define T_   2048
#define H_   16
#define MTOT (B_ * T_)          // 8192 rows
#define NQKV 3072               // fused QKV output cols
#define QSC  0.18033688f        // 0.125 * log2(e): fold softmax scale + exp2 conversion into Q

typedef __attribute__((ext_vector_type(8))) __bf16 bf16x8;
typedef __attribute__((ext_vector_type(4))) float f32x4;
typedef __attribute__((ext_vector_type(16))) float f32x16;
typedef __attribute__((ext_vector_type(4))) float f4v;
typedef __attribute__((ext_vector_type(4))) unsigned short us4;
typedef __attribute__((ext_vector_type(8))) unsigned short us8;
typedef __attribute__((ext_vector_type(4))) unsigned int u32x4;

static __device__ __forceinline__ unsigned short f2bf(float f) {
  __hip_bfloat16 h = __float2bfloat16(f);
  return __builtin_bit_cast(unsigned short, h);
}

static __device__ __forceinline__ float fast_exp2(float x) {
#if __has_builtin(__builtin_amdgcn_exp2f)
  return __builtin_amdgcn_exp2f(x);
#else
  float r; asm("v_exp_f32 %0, %1" : "=v"(r) : "v"(x)); return r;
#endif
}

static __device__ __forceinline__ void async16(const void* g, void* l) {
  __builtin_amdgcn_global_load_lds(
      (const __attribute__((address_space(1))) void*)g,
      (__attribute__((address_space(3))) void*)l, 16, 0, 0);
}

// ---------------- fused fp32 -> bf16 convert (x4 vectorized, 1 launch) --------
__global__ __launch_bounds__(256) void cvt_all(
    const float* __restrict__ x, const float* __restrict__ Wq,
    const float* __restrict__ Wk, const float* __restrict__ Wv,
    const float* __restrict__ Wo, unsigned short* __restrict__ xb,
    unsigned short* __restrict__ wqkv, unsigned short* __restrict__ wo) {
  int i = blockIdx.x * blockDim.x + threadIdx.x;
  const float* s; unsigned short* d; int j;
  if (i < 2097152)      { s = x;  d = xb;             j = i; }
  else if (i < 2359296) { s = Wq; d = wqkv;           j = i - 2097152; }
  else if (i < 2621440) { s = Wk; d = wqkv + 1048576; j = i - 2359296; }
  else if (i < 2883584) { s = Wv; d = wqkv + 2097152; j = i - 2621440; }
  else                  { s = Wo; d = wo;             j = i - 2883584; }
  f4v v = reinterpret_cast<const f4v*>(s)[j];
  us4 o;
  o.x = f2bf(v.x); o.y = f2bf(v.y); o.z = f2bf(v.z); o.w = f2bf(v.w);
  reinterpret_cast<us4*>(d)[j] = o;
}

// ---------------- bf16 GEMM (m97 structure), C = A * B^T ----------------------
// MODE 0: bf16 output, cols < 1024 (Q) scaled by QSC.  MODE 1: f32 output + bias.
template <int MODE>
__global__ __launch_bounds__(256) void gemm_bt(
    const unsigned short* __restrict__ A,   // [M][K] bf16 bits
    const unsigned short* __restrict__ Bw,  // [N][K] bf16 bits
    unsigned short* __restrict__ Cb,        // bf16 out (MODE 0)
    float* __restrict__ Cf,                 // f32 out (MODE 1)
    const float* __restrict__ bias,         // MODE 1
    int K, int N) {
  __shared__ __align__(16) unsigned short As[128 * 32];
  __shared__ __align__(16) unsigned short Bs[128 * 32];

  const int t = threadIdx.x;
  const int lane = t & 63;
  const int w = t >> 6;
  const int lr = lane & 15;
  const int lg = lane >> 4;
  const int wm = w >> 1;
  const int wn = w & 1;
  const int m0 = blockIdx.y * 128;
  const int n0 = blockIdx.x * 128;

  f32x4 acc[4][4];
#pragma unroll
  for (int i = 0; i < 4; ++i)
#pragma unroll
    for (int j = 0; j < 4; ++j) acc[i][j] = (f32x4){0.f, 0.f, 0.f, 0.f};

  const int srow = t >> 2;          // 0..63
  const int scol = (t & 3) * 8;     // 0,8,16,24 elems
  const unsigned short* ga = A + (size_t)(m0 + srow) * K + scol;
  const unsigned short* gb = Bw + (size_t)(n0 + srow) * K + scol;

  for (int k0 = 0; k0 < K; k0 += 32) {
    async16(ga + k0,                  &As[t * 8]);
    async16(ga + k0 + (size_t)64 * K, &As[2048 + t * 8]);
    async16(gb + k0,                  &Bs[t * 8]);
    async16(gb + k0 + (size_t)64 * K, &Bs[2048 + t * 8]);
    __syncthreads();

    bf16x8 af[4], bfr[4];
#pragma unroll
    for (int mi = 0; mi < 4; ++mi)
      af[mi] = *(const bf16x8*)&As[(wm * 64 + mi * 16 + lr) * 32 + lg * 8];
#pragma unroll
    for (int ni = 0; ni < 4; ++ni)
      bfr[ni] = *(const bf16x8*)&Bs[(wn * 64 + ni * 16 + lr) * 32 + lg * 8];
#pragma unroll
    for (int mi = 0; mi < 4; ++mi)
#pragma unroll
      for (int ni = 0; ni < 4; ++ni)
        acc[mi][ni] = __builtin_amdgcn_mfma_f32_16x16x32_bf16(
            af[mi], bfr[ni], acc[mi][ni], 0, 0, 0);
    __syncthreads();
  }

  // epilogue: D layout col=lane&15, row=(lane>>4)*4+r
#pragma unroll
  for (int mi = 0; mi < 4; ++mi) {
    const int row = m0 + wm * 64 + mi * 16 + lg * 4;
#pragma unroll
    for (int ni = 0; ni < 4; ++ni) {
      const int col = n0 + wn * 64 + ni * 16 + lr;
#pragma unroll
      for (int r = 0; r < 4; ++r) {
        if (MODE == 1) {
          Cf[(size_t)(row + r) * N + col] = acc[mi][ni][r] + bias[col];
        } else {
          float v = acc[mi][ni][r];
          if (col < 1024) v *= QSC;   // pre-scale Q for exp2-space softmax
          Cb[(size_t)(row + r) * N + col] = f2bf(v);
        }
      }
    }
  }
}

// ---------------- causal flash attention (8 waves x 32 q-rows, 32x32 MFMA) ----
// qkv: [8192][3072] bf16 (cols: 0..1023 Q (pre-scaled), 1024..2047 K, 2048..3071 V)
// ob : [8192][1024] bf16 attention output (col = h*64+d)
//
// Swapped-operand scheme: S^T = K·Q^T via mfma(A=K, B=Q) -> lane owns q-col
// (lane&31); softmax fully in-register (tree-reduced, defer-max THR=8,
// raw v_exp_f32); P redistributed via cvt_pk + v_permlane32_swap_b32;
// O^T = V^T·P^T. KVBLK=128 double-buffered staging.
// Block->qg mapping pairs co-resident blocks (2/CU) so work sums are equal:
// (7,0),(6,1),(5,2),(4,3) instead of (7,3),(6,2),(5,1),(4,0).
__global__ __launch_bounds__(512, 2) void attn_kernel(
    const unsigned short* __restrict__ qkv, unsigned short* __restrict__ ob) {
  const int bid = blockIdx.x;
  const int qg = (bid < 256) ? (7 - (bid >> 6)) : ((bid - 256) >> 6);
  const int pair = bid & 63;
  const int b = pair >> 4;
  const int h = pair & 15;
  const int t = threadIdx.x;
  const int w = t >> 6;
  const int lane = t & 63;
  const int l31 = lane & 31;
  const int hi = lane >> 5;

  const int q0w = qg * 256 + w * 32;
  const int myBound = qg * 4 + (w >> 1);
  const int NT2 = qg * 2 + 2;

  __shared__ __align__(16) unsigned short Ks[2][128 * 64];
  __shared__ __align__(16) unsigned short Vs[2][128 * 64];

  const size_t rowbase = (size_t)(b * T_) * NQKV;

  bf16x8 Qf[4];
  {
    const unsigned short* qp =
        qkv + rowbase + (size_t)(q0w + l31) * NQKV + h * 64 + hi * 8;
#pragma unroll
    for (int m = 0; m < 4; ++m) Qf[m] = *(const bf16x8*)(qp + m * 16);
  }

  const int krow = t >> 3;
  const int kg = (t & 7) ^ (krow & 7);
  const unsigned short* kbase =
      qkv + rowbase + 1024 + h * 64 + kg * 8 + (size_t)krow * NQKV;
  const int kvr = t >> 3;
  const int dc = t & 7;
  const unsigned short* vbase =
      qkv + rowbase + 2048 + h * 64 + dc * 8 + (size_t)kvr * NQKV;

  float m_i = -INFINITY, l_i = 0.f;
  f32x16 o[2];
#pragma unroll
  for (int r = 0; r < 16; ++r) { o[0][r] = 0.f; o[1][r] = 0.f; }

#define VSCATTER(Vb, v0, v1)                                     \
  {                                                              \
    _Pragma("unroll") for (int i = 0; i < 8; ++i) {              \
      const int sw = dc ^ i;                                     \
      const int c0 = (kvr >> 3) ^ sw;                            \
      unsigned short* vp = (Vb) + (dc * 8 + i) * 128 + (kvr & 7);\
      vp[c0 * 8] = (v0)[i];                                      \
      vp[c0 * 8 + 64] = (v1)[i];                                 \
    }                                                            \
  }

  {
    async16(kbase, &Ks[0][t * 8]);
    async16(kbase + (size_t)64 * NQKV, &Ks[0][4096 + t * 8]);
    us8 v0 = *(const us8*)vbase;
    us8 v1 = *(const us8*)(vbase + (size_t)64 * NQKV);
    VSCATTER(&Vs[0][0], v0, v1);
  }

  int cur = 0;
  for (int kt = 0; kt < NT2; ++kt) {
    __syncthreads();

    const bool pf = (kt + 1 < NT2);
    us8 v0, v1;
    if (pf) {
      const size_t off = (size_t)(kt + 1) * 128 * NQKV;
      async16(kbase + off, &Ks[cur ^ 1][t * 8]);
      async16(kbase + off + (size_t)64 * NQKV, &Ks[cur ^ 1][4096 + t * 8]);
      v0 = *(const us8*)(vbase + off);
      v1 = *(const us8*)(vbase + off + (size_t)64 * NQKV);
    }

    const unsigned short* Kb = Ks[cur];
    const unsigned short* Vb = Vs[cur];

#pragma unroll
    for (int kh = 0; kh < 2; ++kh) {
      const int kt64 = kt * 2 + kh;
      if (kt64 > myBound) break;

      f32x16 a0, a1;
#pragma unroll
      for (int r = 0; r < 16; ++r) { a0[r] = 0.f; a1[r] = 0.f; }
      {
        const int rb0 = (kh * 64 + l31) * 64;
        const int rb1 = (kh * 64 + 32 + l31) * 64;
        const int r7 = l31 & 7;
        __builtin_amdgcn_s_setprio(1);
#pragma unroll
        for (int m = 0; m < 4; ++m) {
          const int c = (((m << 1) | hi) ^ r7) * 8;
          bf16x8 kf0 = *(const bf16x8*)&Kb[rb0 + c];
          bf16x8 kf1 = *(const bf16x8*)&Kb[rb1 + c];
          a0 = __builtin_amdgcn_mfma_f32_32x32x16_bf16(kf0, Qf[m], a0, 0, 0, 0);
          a1 = __builtin_amdgcn_mfma_f32_32x32x16_bf16(kf1, Qf[m], a1, 0, 0, 0);
        }
        __builtin_amdgcn_s_setprio(0);
      }

      if (kt64 == myBound) {
        const int qglob = q0w + l31;
#pragma unroll
        for (int r = 0; r < 16; ++r) {
          const int kvb = kt64 * 64 + (r & 3) + ((r >> 2) << 3) + (hi << 2);
          if (kvb > qglob) a0[r] = -INFINITY;
          if (kvb + 32 > qglob) a1[r] = -INFINITY;
        }
      }

      // online softmax: tree max, defer-max (THR=8 in log2 space)
      float m8[8];
#pragma unroll
      for (int j = 0; j < 8; ++j)
        m8[j] = fmaxf(fmaxf(a0[j], a0[j + 8]), fmaxf(a1[j], a1[j + 8]));
      float pmax = fmaxf(fmaxf(fmaxf(m8[0], m8[4]), fmaxf(m8[1], m8[5])),
                         fmaxf(fmaxf(m8[2], m8[6]), fmaxf(m8[3], m8[7])));
      pmax = fmaxf(pmax, __shfl_xor(pmax, 32));
      if (__any(pmax > m_i + 8.f)) {
        const float mnew = fmaxf(m_i, pmax);
        const float al = fast_exp2(m_i - mnew);
        m_i = mnew;
        l_i *= al;
#pragma unroll
        for (int r = 0; r < 16; ++r) { o[0][r] *= al; o[1][r] *= al; }
      }

#pragma unroll
      for (int r = 0; r < 16; ++r) {
        a0[r] = fast_exp2(a0[r] - m_i);
        a1[r] = fast_exp2(a1[r] - m_i);
      }
      float s8[8];
#pragma unroll
      for (int j = 0; j < 8; ++j)
        s8[j] = (a0[j] + a0[j + 8]) + (a1[j] + a1[j + 8]);
      float rs = ((s8[0] + s8[1]) + (s8[2] + s8[3])) +
                 ((s8[4] + s8[5]) + (s8[6] + s8[7]));
      rs += __shfl_xor(rs, 32);
      l_i += rs;

      bf16x8 Pf[4];
#pragma unroll
      for (int m = 0; m < 4; ++m) {
        const int rb2 = (m & 1) * 8;
        uint32_t u0, u1, u2, u3;
        const f32x16& s = (m >> 1) ? a1 : a0;
        asm("v_cvt_pk_bf16_f32 %0, %1, %2" : "=v"(u0) : "v"(s[rb2 + 0]), "v"(s[rb2 + 1]));
        asm("v_cvt_pk_bf16_f32 %0, %1, %2" : "=v"(u1) : "v"(s[rb2 + 2]), "v"(s[rb2 + 3]));
        asm("v_cvt_pk_bf16_f32 %0, %1, %2" : "=v"(u2) : "v"(s[rb2 + 4]), "v"(s[rb2 + 5]));
        asm("v_cvt_pk_bf16_f32 %0, %1, %2" : "=v"(u3) : "v"(s[rb2 + 6]), "v"(s[rb2 + 7]));
        asm("v_permlane32_swap_b32 %0, %1" : "+v"(u0), "+v"(u2));
        asm("v_permlane32_swap_b32 %0, %1" : "+v"(u1), "+v"(u3));
        u32x4 pw = {u0, u1, u2, u3};
        Pf[m] = __builtin_bit_cast(bf16x8, pw);
      }

      __builtin_amdgcn_s_setprio(1);
#pragma unroll
      for (int dt = 0; dt < 2; ++dt) {
        const int d = dt * 32 + l31;
        const int base = d * 128 + kh * 64;
        const int dsw = ((d >> 3) ^ d) & 7;
#pragma unroll
        for (int m = 0; m < 4; ++m) {
          bf16x8 vf = *(const bf16x8*)&Vb[base + ((((m << 1) | hi) ^ dsw) & 7) * 8];
          o[dt] = __builtin_amdgcn_mfma_f32_32x32x16_bf16(vf, Pf[m], o[dt], 0, 0, 0);
        }
      }
      __builtin_amdgcn_s_setprio(0);
    }

    if (pf) VSCATTER(&Vs[cur ^ 1][0], v0, v1);
    cur ^= 1;
  }

  const float rl = 1.0f / l_i;
#pragma unroll
  for (int dt = 0; dt < 2; ++dt) {
    float s[16];
#pragma unroll
    for (int r = 0; r < 16; ++r) s[r] = o[dt][r] * rl;
    uint32_t u[8];
#pragma unroll
    for (int p = 0; p < 8; ++p)
      asm("v_cvt_pk_bf16_f32 %0, %1, %2" : "=v"(u[p]) : "v"(s[2 * p]), "v"(s[2 * p + 1]));
    asm("v_permlane32_swap_b32 %0, %1" : "+v"(u[0]), "+v"(u[2]));
    asm("v_permlane32_swap_b32 %0, %1" : "+v"(u[1]), "+v"(u[3]));
    asm("v_permlane32_swap_b32 %0, %1" : "+v"(u[4]), "+v"(u[6]));
    asm("v_permlane32_swap_b32 %0, %1" : "+v"(u[5]), "+v"(u[7]));
    unsigned short* op =
        ob + (size_t)(b * T_ + q0w + l31) * 1024 + h * 64 + dt * 32 + hi * 8;
    u32x4 c0 = {u[0], u[1], u[2], u[3]};
    u32x4 c1 = {u[4], u[5], u[6], u[7]};
    *(u32x4*)op = c0;
    *(u32x4*)(op + 16) = c1;
  }
}

// ---------------- host launch ----------------
extern "C" void kernel_launch(void* const* d_in, const int* in_sizes, int n_in,
                              void* d_out, int out_size, void* d_ws,
                              size_t ws_size, hipStream_t stream) {
  const float* x = (const float*)d_in[0];
  const float* Wq = (const float*)d_in[1];
  const float* Wk = (const float*)d_in[2];
  const float* Wv = (const float*)d_in[3];
  const float* Wo = (const float*)d_in[4];
  const float* bo = (const float*)d_in[5];
  float* out = (float*)d_out;

  char* ws = (char*)d_ws;
  unsigned short* xb   = (unsigned short*)(ws + 0);          // 16 MB
  unsigned short* wqkv = (unsigned short*)(ws + 16777216);   // 6 MB
  unsigned short* wo   = (unsigned short*)(ws + 23068672);   // 2 MB
  unsigned short* qkv  = (unsigned short*)(ws + 25165824);   // 48 MB
  unsigned short* ob   = (unsigned short*)(ws + 75497472);   // 16 MB
  if (ws_size < 92274688u) return;

  cvt_all<<<12288, 256, 0, stream>>>(x, Wq, Wk, Wv, Wo, xb, wqkv, wo);

  // fused QKV projection (m97 structure, proven ~912 TF)
  gemm_bt<0><<<dim3(NQKV / 128, MTOT / 128), 256, 0, stream>>>(
      xb, wqkv, qkv, nullptr, nullptr, 1024, NQKV);

  // causal flash attention (balanced block pairing)
  attn_kernel<<<dim3(512), 512, 0, stream>>>(qkv, ob);

  // output projection + bias
  gemm_bt<1><<<dim3(1024 / 128, MTOT / 128), 256, 0, stream>>>(
      ob, wo, nullptr, out, bo, 1024, 1024);
}